// Round 5
// baseline (218.980 us; speedup 1.0000x reference)
//
#include <hip/hip_runtime.h>
#include <hip/hip_bf16.h>
#include <stdint.h>

typedef unsigned short u16;
typedef unsigned int   u32;
typedef short bf16x8 __attribute__((ext_vector_type(8)));
typedef float f32x4  __attribute__((ext_vector_type(4)));
typedef float f32x16 __attribute__((ext_vector_type(16)));

#define MFMA16(A,B,C) __builtin_amdgcn_mfma_f32_16x16x32_bf16((A),(B),(C),0,0,0)
#define MFMA32(A,B,C) __builtin_amdgcn_mfma_f32_32x32x16_bf16((A),(B),(C),0,0,0)

// fp32 -> bf16 round-to-nearest-even
__device__ __forceinline__ u16 f2b(float x) {
  u32 u = __float_as_uint(x);
  u += 0x7fffu + ((u >> 16) & 1u);
  return (u16)(u >> 16);
}
__device__ __forceinline__ u32 cvtpk(float lo, float hi) {
  u32 r;
  asm("v_cvt_pk_bf16_f32 %0, %1, %2" : "=v"(r) : "v"(lo), "v"(hi));
  return r;
}

typedef __attribute__((address_space(1))) const void glob_void;
typedef __attribute__((address_space(3))) void lds_void;
__device__ __forceinline__ void gld16(const void* g, void* s) {
  __builtin_amdgcn_global_load_lds((glob_void*)g, (lds_void*)s, 16, 0, 0);
}

// ---------------------------------------------------------------- convert
__global__ void cvt_bf16(const float4* __restrict__ in, ushort4* __restrict__ out, int n4) {
  int stride = gridDim.x * blockDim.x;
  for (int i = blockIdx.x * blockDim.x + threadIdx.x; i < n4; i += stride) {
    float4 v = in[i];
    ushort4 o;
    o.x = f2b(v.x); o.y = f2b(v.y); o.z = f2b(v.z); o.w = f2b(v.w);
    out[i] = o;
  }
}

// ---------------------------------------------------------------- QKV GEMM
// T3-min pipeline: 2x LDS double-buffer; issue next K-step's global_load_lds
// BEFORE computing current; one counted-drain + raw s_barrier per step.
// LDS 16B-granule XOR-swizzle (phys = logical ^ ((row>>1)&3)), both-sides.
__global__ __launch_bounds__(256) void gemm_qkv(
    const u16* __restrict__ xb, const u16* __restrict__ wb,
    u16* __restrict__ q, u16* __restrict__ k, u16* __restrict__ vt)
{
  __shared__ u16 lA[2][128*32];
  __shared__ u16 lB[2][128*32];
  const int tid = threadIdx.x;
  const int lane = tid & 63;
  const int wv = tid >> 6;
  const int wr = wv >> 1, wc = wv & 1;
  const int m0 = blockIdx.x << 7;
  const int o0 = blockIdx.y << 7;
  f32x4 acc[4][4] = {};
  const int srow = tid >> 2;
  const int sb   = (((tid & 3) ^ ((srow >> 1) & 3)) << 4);
  const char* gA0 = (const char*)(xb + (size_t)(m0 + srow)      * 768) + sb;
  const char* gA1 = (const char*)(xb + (size_t)(m0 + 64 + srow) * 768) + sb;
  const char* gB0 = (const char*)(wb + (size_t)(o0 + srow)      * 768) + sb;
  const char* gB1 = (const char*)(wb + (size_t)(o0 + 64 + srow) * 768) + sb;
  char* sA = (char*)lA + tid * 16;
  char* sB = (char*)lB + tid * 16;
  const int frow = lane & 15;
  const int fk   = (((lane >> 4) ^ ((frow >> 1) & 3)) << 4);

#define QKV_STAGE(buf, kt) do { const int kb_ = (kt) << 6; const int bo_ = (buf) << 13; \
    gld16(gA0 + kb_, sA + bo_); gld16(gA1 + kb_, sA + bo_ + 4096); \
    gld16(gB0 + kb_, sB + bo_); gld16(gB1 + kb_, sB + bo_ + 4096); } while (0)

  QKV_STAGE(0, 0);
  asm volatile("s_waitcnt vmcnt(0) lgkmcnt(0)" ::: "memory");
  __builtin_amdgcn_s_barrier();
  for (int kt = 0; kt < 24; ++kt) {
    const int cur = kt & 1;
    if (kt < 23) QKV_STAGE(cur ^ 1, kt + 1);
    const char* bA = (const char*)lA + (cur << 13);
    const char* bB = (const char*)lB + (cur << 13);
    bf16x8 af[4], bfr[4];
#pragma unroll
    for (int m = 0; m < 4; ++m)
      af[m] = *(const bf16x8*)(bA + ((wr*64 + m*16 + frow) << 6) + fk);
#pragma unroll
    for (int n = 0; n < 4; ++n)
      bfr[n] = *(const bf16x8*)(bB + ((wc*64 + n*16 + frow) << 6) + fk);
#pragma unroll
    for (int m = 0; m < 4; ++m)
#pragma unroll
      for (int n = 0; n < 4; ++n)
        acc[m][n] = MFMA16(af[m], bfr[n], acc[m][n]);
    asm volatile("s_waitcnt vmcnt(0) lgkmcnt(0)" ::: "memory");
    __builtin_amdgcn_s_barrier();
  }
  const int which = o0 / 768;
  const int ob = o0 - which * 768;
  const float QSCALE = 0.18033688011112042f; // 0.125 * log2(e)
#pragma unroll
  for (int n = 0; n < 4; ++n) {
    const int go = ob + wc*64 + n*16 + (lane & 15);
    const int h = go >> 6, d = go & 63;
#pragma unroll
    for (int m = 0; m < 4; ++m) {
      const int gm0 = m0 + wr*64 + m*16 + ((lane >> 4) << 2);
      const int b = gm0 >> 10, nn0 = gm0 & 1023;
      if (which == 2) {
        ushort4 o4;
        o4.x = f2b(acc[m][n][0]); o4.y = f2b(acc[m][n][1]);
        o4.z = f2b(acc[m][n][2]); o4.w = f2b(acc[m][n][3]);
        *(ushort4*)(vt + (((size_t)((b*12 + h)*64 + d)) << 10) + nn0) = o4;
      } else if (which == 0) {
#pragma unroll
        for (int r = 0; r < 4; ++r)
          q[((size_t)((b*12 + h)*1024 + nn0 + r) << 6) + d] = f2b(acc[m][n][r] * QSCALE);
      } else {
#pragma unroll
        for (int r = 0; r < 4; ++r)
          k[((size_t)((b*12 + h)*1024 + nn0 + r) << 6) + d] = f2b(acc[m][n][r]);
      }
    }
  }
}

// ---------------------------------------------------------------- attention
// grid (bh=192, qt=8): flat%8 = bh%8 -> q-tiles of one head share an XCD.
// K/V double-buffered, T3-min pipeline. Defer-max (T13). VALU diet:
// tree-max (depth 5), row-sum via MFMA-ones (accl[0] carries l), setprio (T5).
__global__ __launch_bounds__(256) void attn_fwd(
    const u16* __restrict__ q, const u16* __restrict__ kk,
    const u16* __restrict__ vt, u16* __restrict__ ao)
{
  __shared__ u16 lK[2][64*64];
  __shared__ u16 lV[2][64*64];
  const int tid = threadIdx.x, lane = tid & 63, wv = tid >> 6;
  const int l31 = lane & 31, hh = lane >> 5;
  const int bh = blockIdx.x, qt = blockIdx.y;
  const u16*  qb = q  + ((size_t)bh << 16);
  const char* kg = (const char*)(kk + ((size_t)bh << 16));
  const char* vg = (const char*)(vt + ((size_t)bh << 16));
  const int qrow = (qt << 7) + (wv << 5) + l31;
  bf16x8 qreg[4];
#pragma unroll
  for (int c = 0; c < 4; ++c)
    qreg[c] = *(const bf16x8*)((const char*)qb + (size_t)qrow*128 + c*32 + hh*16);
  const short ONE = (short)0x3f80;
  const bf16x8 ones = {ONE, ONE, ONE, ONE, ONE, ONE, ONE, ONE};
  f32x16 ot[2] = {};
  f32x16 accl = {};          // accl[0] = running softmax denominator (all regs equal)
  float mrun = -1e30f;
  const int o1 = tid << 4, o2 = o1 + 4096;
  const int ko1 = o1 ^ (((o1 >> 7) & 7) << 4);
  const int ko2 = o2 ^ (((o2 >> 7) & 7) << 4);
  const int d1 = o1 >> 7, d2 = o2 >> 7;
  const int vo1 = d1*2048 + ((o1 & 127) ^ ((d1 & 7) << 4));
  const int vo2 = d2*2048 + ((o2 & 127) ^ ((d2 & 7) << 4));
  char* sK = (char*)lK;
  char* sV = (char*)lV;
  // loop-invariant fragment-read offsets: row&7 == l31&7 for both tt halves
  const int sw   = (l31 & 7) << 4;
  const int off0 = ((0 << 5) + (hh << 4)) ^ sw;
  const int off1 = ((1 << 5) + (hh << 4)) ^ sw;
  const int off2 = ((2 << 5) + (hh << 4)) ^ sw;
  const int off3 = ((3 << 5) + (hh << 4)) ^ sw;
  const int rb0  = l31 << 7;
  const int rb1  = (32 + l31) << 7;

#define ATTN_STAGE(buf, t) do { const int bo_ = (buf) << 13; \
    gld16(kg + ((t) << 13) + ko1, sK + bo_ + o1); \
    gld16(kg + ((t) << 13) + ko2, sK + bo_ + o2); \
    gld16(vg + ((t) << 7) + vo1, sV + bo_ + o1); \
    gld16(vg + ((t) << 7) + vo2, sV + bo_ + o2); } while (0)

  ATTN_STAGE(0, 0);
  asm volatile("s_waitcnt vmcnt(0) lgkmcnt(0)" ::: "memory");
  __builtin_amdgcn_s_barrier();
  for (int t0 = 0; t0 < 16; ++t0) {
    const int cur = t0 & 1;
    if (t0 < 15) ATTN_STAGE(cur ^ 1, t0 + 1);
    const char* bK = (const char*)lK + (cur << 13);
    const char* bV = (const char*)lV + (cur << 13);
    f32x16 s[2] = {};
    __builtin_amdgcn_s_setprio(1);
#pragma unroll
    for (int tt = 0; tt < 2; ++tt) {
      const char* kr = bK + (tt ? rb1 : rb0);
      s[tt] = MFMA32(*(const bf16x8*)(kr + off0), qreg[0], s[tt]);
      s[tt] = MFMA32(*(const bf16x8*)(kr + off1), qreg[1], s[tt]);
      s[tt] = MFMA32(*(const bf16x8*)(kr + off2), qreg[2], s[tt]);
      s[tt] = MFMA32(*(const bf16x8*)(kr + off3), qreg[3], s[tt]);
    }
    __builtin_amdgcn_s_setprio(0);
    // tree max over the 32 scores (depth 5)
    float t8[8];
#pragma unroll
    for (int r = 0; r < 8; ++r)
      t8[r] = fmaxf(fmaxf(s[0][r], s[0][r+8]), fmaxf(s[1][r], s[1][r+8]));
    const float ta = fmaxf(fmaxf(t8[0], t8[1]), fmaxf(t8[2], t8[3]));
    const float tb = fmaxf(fmaxf(t8[4], t8[5]), fmaxf(t8[6], t8[7]));
    float mloc = fmaxf(ta, tb);
    if (!__all(mloc <= mrun + 8.f)) {      // defer-max (T13)
      mloc = fmaxf(mloc, __shfl_xor(mloc, 32));
      const float mnew  = fmaxf(mrun, mloc);
      const float alpha = __builtin_amdgcn_exp2f(mrun - mnew);
      accl[0] *= alpha;                    // only reg0 is ever read
#pragma unroll
      for (int dt = 0; dt < 2; ++dt)
#pragma unroll
        for (int r = 0; r < 16; ++r) ot[dt][r] *= alpha;
      mrun = mnew;
    }
#pragma unroll
    for (int tt = 0; tt < 2; ++tt)
#pragma unroll
      for (int r = 0; r < 16; ++r)
        s[tt][r] = __builtin_amdgcn_exp2f(s[tt][r] - mrun);
    // P -> PV B-frags (cvt_pk + permlane32_swap, T12)
    bf16x8 pb[4];
#pragma unroll
    for (int tt = 0; tt < 2; ++tt) {
      u32 x0 = cvtpk(s[tt][0],  s[tt][1]);
      u32 y0 = cvtpk(s[tt][4],  s[tt][5]);
      u32 x1 = cvtpk(s[tt][2],  s[tt][3]);
      u32 y1 = cvtpk(s[tt][6],  s[tt][7]);
      asm("v_permlane32_swap_b32 %0, %1" : "+v"(x0), "+v"(y0));
      asm("v_permlane32_swap_b32 %0, %1" : "+v"(x1), "+v"(y1));
      u32 x2 = cvtpk(s[tt][8],  s[tt][9]);
      u32 y2 = cvtpk(s[tt][12], s[tt][13]);
      u32 x3 = cvtpk(s[tt][10], s[tt][11]);
      u32 y3 = cvtpk(s[tt][14], s[tt][15]);
      asm("v_permlane32_swap_b32 %0, %1" : "+v"(x2), "+v"(y2));
      asm("v_permlane32_swap_b32 %0, %1" : "+v"(x3), "+v"(y3));
      union { u32 u[4]; bf16x8 v; } a, b;
      a.u[0] = x0; a.u[1] = x1; a.u[2] = y0; a.u[3] = y1;
      b.u[0] = x2; b.u[1] = x3; b.u[2] = y2; b.u[3] = y3;
      pb[2*tt]     = a.v;
      pb[2*tt + 1] = b.v;
    }
    __builtin_amdgcn_s_setprio(1);
    // denominator via MFMA-ones: every reg of accl += sum_kv P (row-independent)
    accl = MFMA32(ones, pb[0], accl);
    accl = MFMA32(ones, pb[1], accl);
    accl = MFMA32(ones, pb[2], accl);
    accl = MFMA32(ones, pb[3], accl);
    // PV: O^T[d][q] += VT[d][kv] * P^T[kv][q]
#pragma unroll
    for (int dt = 0; dt < 2; ++dt) {
      const char* vr = bV + (dt ? rb1 : rb0);
      ot[dt] = MFMA32(*(const bf16x8*)(vr + off0), pb[0], ot[dt]);
      ot[dt] = MFMA32(*(const bf16x8*)(vr + off1), pb[1], ot[dt]);
      ot[dt] = MFMA32(*(const bf16x8*)(vr + off2), pb[2], ot[dt]);
      ot[dt] = MFMA32(*(const bf16x8*)(vr + off3), pb[3], ot[dt]);
    }
    __builtin_amdgcn_s_setprio(0);
    asm volatile("s_waitcnt vmcnt(0) lgkmcnt(0)" ::: "memory");
    __builtin_amdgcn_s_barrier();
  }
  const float linv = 1.f / accl[0];
  const int b = bh / 12, h = bh - b * 12;
  u16* po = ao + ((size_t)(b*1024 + qrow)) * 768 + h*64;
#pragma unroll
  for (int dt = 0; dt < 2; ++dt) {
#pragma unroll
    for (int g = 0; g < 4; ++g) {
      ushort4 o4;
      o4.x = f2b(ot[dt][4*g + 0] * linv);
      o4.y = f2b(ot[dt][4*g + 1] * linv);
      o4.z = f2b(ot[dt][4*g + 2] * linv);
      o4.w = f2b(ot[dt][4*g + 3] * linv);
      *(ushort4*)(po + dt*32 + g*8 + hh*4) = o4;
    }
  }
}

// ---------------------------------------------------------------- proj GEMM
__global__ __launch_bounds__(256) void gemm_proj(
    const u16* __restrict__ ab, const u16* __restrict__ wb,
    const float* __restrict__ bias, float* __restrict__ out)
{
  __shared__ u16 lA[2][128*32];
  __shared__ u16 lB[2][128*32];
  const int tid = threadIdx.x;
  const int lane = tid & 63;
  const int wv = tid >> 6;
  const int wr = wv >> 1, wc = wv & 1;
  const int m0 = blockIdx.x << 7;
  const int o0 = blockIdx.y << 7;
  f32x4 acc[4][4] = {};
  const int srow = tid >> 2;
  const int sb   = (((tid & 3) ^ ((srow >> 1) & 3)) << 4);
  const char* gA0 = (const char*)(ab + (size_t)(m0 + srow)      * 768) + sb;
  const char* gA1 = (const char*)(ab + (size_t)(m0 + 64 + srow) * 768) + sb;
  const char* gB0 = (const char*)(wb + (size_t)(o0 + srow)      * 768) + sb;
  const char* gB1 = (const char*)(wb + (size_t)(o0 + 64 + srow) * 768) + sb;
  char* sA = (char*)lA + tid * 16;
  char* sB = (char*)lB + tid * 16;
  const int frow = lane & 15;
  const int fk   = (((lane >> 4) ^ ((frow >> 1) & 3)) << 4);

  QKV_STAGE(0, 0);
  asm volatile("s_waitcnt vmcnt(0) lgkmcnt(0)" ::: "memory");
  __builtin_amdgcn_s_barrier();
  for (int kt = 0; kt < 24; ++kt) {
    const int cur = kt & 1;
    if (kt < 23) QKV_STAGE(cur ^ 1, kt + 1);
    const char* bA = (const char*)lA + (cur << 13);
    const char* bB = (const char*)lB + (cur << 13);
    bf16x8 af[4], bfr[4];
#pragma unroll
    for (int m = 0; m < 4; ++m)
      af[m] = *(const bf16x8*)(bA + ((wr*64 + m*16 + frow) << 6) + fk);
#pragma unroll
    for (int n = 0; n < 4; ++n)
      bfr[n] = *(const bf16x8*)(bB + ((wc*64 + n*16 + frow) << 6) + fk);
#pragma unroll
    for (int m = 0; m < 4; ++m)
#pragma unroll
      for (int n = 0; n < 4; ++n)
        acc[m][n] = MFMA16(af[m], bfr[n], acc[m][n]);
    asm volatile("s_waitcnt vmcnt(0) lgkmcnt(0)" ::: "memory");
    __builtin_amdgcn_s_barrier();
  }
#pragma unroll
  for (int n = 0; n < 4; ++n) {
    const int go = o0 + wc*64 + n*16 + (lane & 15);
    const float bv = bias[go];
#pragma unroll
    for (int m = 0; m < 4; ++m) {
#pragma unroll
      for (int r = 0; r < 4; ++r) {
        const int gm = m0 + wr*64 + m*16 + ((lane >> 4) << 2) + r;
        out[(size_t)gm * 768 + go] = acc[m][n][r] + bv;
      }
    }
  }
}

// ---------------------------------------------------------------- launch
extern "C" void kernel_launch(void* const* d_in, const int* in_sizes, int n_in,
                              void* d_out, int out_size, void* d_ws, size_t ws_size,
                              hipStream_t stream)
{
  (void)in_sizes; (void)n_in; (void)out_size; (void)ws_size;
  const float* x  = (const float*)d_in[0];
  const float* wq = (const float*)d_in[1];
  const float* wp = (const float*)d_in[2];
  const float* bp = (const float*)d_in[3];
  float* out = (float*)d_out;
  char* ws = (char*)d_ws;
  u16* xb     = (u16*)(ws);              // 25,165,824  x bf16 [16384][768]
  u16* wqkvb  = (u16*)(ws + 25165824);   //  3,538,944  w_qkv bf16
  u16* wprojb = (u16*)(ws + 28704768);   //  1,179,648  w_proj bf16
  u16* qa     = (u16*)(ws + 29884416);   // 25,165,824  q  [192][1024][64] (pre-scaled)
  u16* ka     = (u16*)(ws + 55050240);   // 25,165,824  k  [192][1024][64]
  u16* vta    = (u16*)(ws + 80216064);   // 25,165,824  v^T[192][64][1024]
  u16* ao     = xb;                      // alias: xb dead after gemm_qkv

  cvt_bf16<<<2048, 256, 0, stream>>>((const float4*)x,  (ushort4*)xb,     3145728);
  cvt_bf16<<<1024, 256, 0, stream>>>((const float4*)wq, (ushort4*)wqkvb,   442368);
  cvt_bf16<<< 576, 256, 0, stream>>>((const float4*)wp, (ushort4*)wprojb,  147456);
  gemm_qkv<<<dim3(128, 18), 256, 0, stream>>>(xb, wqkvb, qa, ka, vta);
  attn_fwd<<<dim3(192, 8), 256, 0, stream>>>(qa, ka, vta, ao);
  gemm_proj<<<dim3(128, 6), 256, 0, stream>>>(ao, wprojb, bp, out);
}

// Round 6
// 205.231 us; speedup vs baseline: 1.0670x; 1.0670x over previous
//
#include <hip/hip_runtime.h>
#include <hip/hip_bf16.h>
#include <stdint.h>

typedef unsigned short u16;
typedef unsigned int   u32;
typedef short bf16x8 __attribute__((ext_vector_type(8)));
typedef float f32x4  __attribute__((ext_vector_type(4)));
typedef float f32x16 __attribute__((ext_vector_type(16)));

#define MFMA16(A,B,C) __builtin_amdgcn_mfma_f32_16x16x32_bf16((A),(B),(C),0,0,0)
#define MFMA32(A,B,C) __builtin_amdgcn_mfma_f32_32x32x16_bf16((A),(B),(C),0,0,0)

// fp32 -> bf16 round-to-nearest-even
__device__ __forceinline__ u16 f2b(float x) {
  u32 u = __float_as_uint(x);
  u += 0x7fffu + ((u >> 16) & 1u);
  return (u16)(u >> 16);
}
__device__ __forceinline__ u32 cvtpk(float lo, float hi) {
  u32 r;
  asm("v_cvt_pk_bf16_f32 %0, %1, %2" : "=v"(r) : "v"(lo), "v"(hi));
  return r;
}

typedef __attribute__((address_space(1))) const void glob_void;
typedef __attribute__((address_space(3))) void lds_void;
__device__ __forceinline__ void gld16(const void* g, void* s) {
  __builtin_amdgcn_global_load_lds((glob_void*)g, (lds_void*)s, 16, 0, 0);
}

// ---------------------------------------------------------------- convert
__global__ void cvt_bf16(const float4* __restrict__ in, ushort4* __restrict__ out, int n4) {
  int stride = gridDim.x * blockDim.x;
  for (int i = blockIdx.x * blockDim.x + threadIdx.x; i < n4; i += stride) {
    float4 v = in[i];
    ushort4 o;
    o.x = f2b(v.x); o.y = f2b(v.y); o.z = f2b(v.z); o.w = f2b(v.w);
    out[i] = o;
  }
}

// ---------------------------------------------------------------- QKV GEMM
// T3-min pipeline: 2x LDS double-buffer; issue next K-step's global_load_lds
// BEFORE computing current; one counted-drain + raw s_barrier per step.
// LDS 16B-granule XOR-swizzle (phys = logical ^ ((row>>1)&3)), both-sides.
__global__ __launch_bounds__(256) void gemm_qkv(
    const u16* __restrict__ xb, const u16* __restrict__ wb,
    u16* __restrict__ q, u16* __restrict__ k, u16* __restrict__ vt)
{
  __shared__ u16 lA[2][128*32];
  __shared__ u16 lB[2][128*32];
  const int tid = threadIdx.x;
  const int lane = tid & 63;
  const int wv = tid >> 6;
  const int wr = wv >> 1, wc = wv & 1;
  const int m0 = blockIdx.x << 7;
  const int o0 = blockIdx.y << 7;
  f32x4 acc[4][4] = {};
  const int srow = tid >> 2;
  const int sb   = (((tid & 3) ^ ((srow >> 1) & 3)) << 4);
  const char* gA0 = (const char*)(xb + (size_t)(m0 + srow)      * 768) + sb;
  const char* gA1 = (const char*)(xb + (size_t)(m0 + 64 + srow) * 768) + sb;
  const char* gB0 = (const char*)(wb + (size_t)(o0 + srow)      * 768) + sb;
  const char* gB1 = (const char*)(wb + (size_t)(o0 + 64 + srow) * 768) + sb;
  char* sA = (char*)lA + tid * 16;
  char* sB = (char*)lB + tid * 16;
  const int frow = lane & 15;
  const int fk   = (((lane >> 4) ^ ((frow >> 1) & 3)) << 4);

#define QKV_STAGE(buf, kt) do { const int kb_ = (kt) << 6; const int bo_ = (buf) << 13; \
    gld16(gA0 + kb_, sA + bo_); gld16(gA1 + kb_, sA + bo_ + 4096); \
    gld16(gB0 + kb_, sB + bo_); gld16(gB1 + kb_, sB + bo_ + 4096); } while (0)

  QKV_STAGE(0, 0);
  asm volatile("s_waitcnt vmcnt(0) lgkmcnt(0)" ::: "memory");
  __builtin_amdgcn_s_barrier();
  for (int kt = 0; kt < 24; ++kt) {
    const int cur = kt & 1;
    if (kt < 23) QKV_STAGE(cur ^ 1, kt + 1);
    const char* bA = (const char*)lA + (cur << 13);
    const char* bB = (const char*)lB + (cur << 13);
    bf16x8 af[4], bfr[4];
#pragma unroll
    for (int m = 0; m < 4; ++m)
      af[m] = *(const bf16x8*)(bA + ((wr*64 + m*16 + frow) << 6) + fk);
#pragma unroll
    for (int n = 0; n < 4; ++n)
      bfr[n] = *(const bf16x8*)(bB + ((wc*64 + n*16 + frow) << 6) + fk);
#pragma unroll
    for (int m = 0; m < 4; ++m)
#pragma unroll
      for (int n = 0; n < 4; ++n)
        acc[m][n] = MFMA16(af[m], bfr[n], acc[m][n]);
    asm volatile("s_waitcnt vmcnt(0) lgkmcnt(0)" ::: "memory");
    __builtin_amdgcn_s_barrier();
  }
  const int which = o0 / 768;
  const int ob = o0 - which * 768;
  const float QSCALE = 0.18033688011112042f; // 0.125 * log2(e)
#pragma unroll
  for (int n = 0; n < 4; ++n) {
    const int go = ob + wc*64 + n*16 + (lane & 15);
    const int h = go >> 6, d = go & 63;
#pragma unroll
    for (int m = 0; m < 4; ++m) {
      const int gm0 = m0 + wr*64 + m*16 + ((lane >> 4) << 2);
      const int b = gm0 >> 10, nn0 = gm0 & 1023;
      if (which == 2) {
        ushort4 o4;
        o4.x = f2b(acc[m][n][0]); o4.y = f2b(acc[m][n][1]);
        o4.z = f2b(acc[m][n][2]); o4.w = f2b(acc[m][n][3]);
        *(ushort4*)(vt + (((size_t)((b*12 + h)*64 + d)) << 10) + nn0) = o4;
      } else if (which == 0) {
#pragma unroll
        for (int r = 0; r < 4; ++r)
          q[((size_t)((b*12 + h)*1024 + nn0 + r) << 6) + d] = f2b(acc[m][n][r] * QSCALE);
      } else {
#pragma unroll
        for (int r = 0; r < 4; ++r)
          k[((size_t)((b*12 + h)*1024 + nn0 + r) << 6) + d] = f2b(acc[m][n][r]);
      }
    }
  }
}

// ---------------------------------------------------------------- attention
// 8 waves x 32 q-rows = QBLK 256 (occupancy lever: 4 blocks/CU = 32 waves =
// 100% vs 4-wave's 20-wave LDS-bound ceiling; grid 192x4 = exactly 3/CU).
// Wave core = round-4 structure verbatim (97 us baseline): swapped-QK 32x32,
// defer-max (T13), cvt_pk+permlane (T12). grid flat%8 = bh%8 -> XCD-grouped.
// Staging: 512 thr x 16B = one 8KB tile per array per shot (2 gld16/thread).
__global__ __launch_bounds__(512) void attn_fwd(
    const u16* __restrict__ q, const u16* __restrict__ kk,
    const u16* __restrict__ vt, u16* __restrict__ ao)
{
  __shared__ u16 lK[2][64*64];
  __shared__ u16 lV[2][64*64];
  const int tid = threadIdx.x, lane = tid & 63, wv = tid >> 6;
  const int l31 = lane & 31, hh = lane >> 5;
  const int bh = blockIdx.x, qt = blockIdx.y;
  const u16*  qb = q  + ((size_t)bh << 16);
  const char* kg = (const char*)(kk + ((size_t)bh << 16));
  const char* vg = (const char*)(vt + ((size_t)bh << 16));
  const int qrow = (qt << 8) + (wv << 5) + l31;
  bf16x8 qreg[4];
#pragma unroll
  for (int c = 0; c < 4; ++c)
    qreg[c] = *(const bf16x8*)((const char*)qb + (size_t)qrow*128 + c*32 + hh*16);
  f32x16 ot[2] = {};
  float mrun = -1e30f, lrun = 0.f;
  // staging offsets: tid in [0,512) covers the full 8 KB tile at 16 B each
  const int o1 = tid << 4;
  const int ko1 = o1 ^ (((o1 >> 7) & 7) << 4);
  const int d1 = o1 >> 7;
  const int vo1 = d1*2048 + ((o1 & 127) ^ ((d1 & 7) << 4));
  char* sK = (char*)lK;
  char* sV = (char*)lV;

#define ATTN_STAGE(buf, t) do { const int bo_ = (buf) << 13; \
    gld16(kg + ((t) << 13) + ko1, sK + bo_ + o1); \
    gld16(vg + ((t) << 7) + vo1, sV + bo_ + o1); } while (0)

  ATTN_STAGE(0, 0);
  asm volatile("s_waitcnt vmcnt(0) lgkmcnt(0)" ::: "memory");
  __builtin_amdgcn_s_barrier();
  for (int t0 = 0; t0 < 16; ++t0) {
    const int cur = t0 & 1;
    if (t0 < 15) ATTN_STAGE(cur ^ 1, t0 + 1);
    const char* bK = (const char*)lK + (cur << 13);
    const char* bV = (const char*)lV + (cur << 13);
    f32x16 s[2] = {};
#pragma unroll
    for (int tt = 0; tt < 2; ++tt) {
      const int row = (tt << 5) + l31;
      const int rb = row << 7;
      const int sw = (row & 7) << 4;
#pragma unroll
      for (int c = 0; c < 4; ++c) {
        bf16x8 kf = *(const bf16x8*)(bK + rb + (((c << 5) + (hh << 4)) ^ sw));
        s[tt] = MFMA32(kf, qreg[c], s[tt]);
      }
    }
    float mloc = s[0][0];
#pragma unroll
    for (int tt = 0; tt < 2; ++tt)
#pragma unroll
      for (int r = 0; r < 16; ++r) mloc = fmaxf(mloc, s[tt][r]);
    if (!__all(mloc <= mrun + 8.f)) {      // defer-max (T13)
      mloc = fmaxf(mloc, __shfl_xor(mloc, 32));
      const float mnew  = fmaxf(mrun, mloc);
      const float alpha = __builtin_amdgcn_exp2f(mrun - mnew);
      lrun *= alpha;
#pragma unroll
      for (int dt = 0; dt < 2; ++dt)
#pragma unroll
        for (int r = 0; r < 16; ++r) ot[dt][r] *= alpha;
      mrun = mnew;
    }
    float sum = 0.f;
#pragma unroll
    for (int tt = 0; tt < 2; ++tt)
#pragma unroll
      for (int r = 0; r < 16; ++r) {
        s[tt][r] = __builtin_amdgcn_exp2f(s[tt][r] - mrun);
        sum += s[tt][r];
      }
    sum += __shfl_xor(sum, 32);
    lrun += sum;
    bf16x8 pb[4];
#pragma unroll
    for (int tt = 0; tt < 2; ++tt) {
      u32 x0 = cvtpk(s[tt][0],  s[tt][1]);
      u32 y0 = cvtpk(s[tt][4],  s[tt][5]);
      u32 x1 = cvtpk(s[tt][2],  s[tt][3]);
      u32 y1 = cvtpk(s[tt][6],  s[tt][7]);
      asm("v_permlane32_swap_b32 %0, %1" : "+v"(x0), "+v"(y0));
      asm("v_permlane32_swap_b32 %0, %1" : "+v"(x1), "+v"(y1));
      u32 x2 = cvtpk(s[tt][8],  s[tt][9]);
      u32 y2 = cvtpk(s[tt][12], s[tt][13]);
      u32 x3 = cvtpk(s[tt][10], s[tt][11]);
      u32 y3 = cvtpk(s[tt][14], s[tt][15]);
      asm("v_permlane32_swap_b32 %0, %1" : "+v"(x2), "+v"(y2));
      asm("v_permlane32_swap_b32 %0, %1" : "+v"(x3), "+v"(y3));
      union { u32 u[4]; bf16x8 v; } a, b;
      a.u[0] = x0; a.u[1] = x1; a.u[2] = y0; a.u[3] = y1;
      b.u[0] = x2; b.u[1] = x3; b.u[2] = y2; b.u[3] = y3;
      pb[2*tt]     = a.v;
      pb[2*tt + 1] = b.v;
    }
#pragma unroll
    for (int dt = 0; dt < 2; ++dt) {
      const int row = (dt << 5) + l31;
      const int rb = row << 7;
      const int sw = (row & 7) << 4;
#pragma unroll
      for (int cc = 0; cc < 4; ++cc) {
        bf16x8 vf = *(const bf16x8*)(bV + rb + (((cc << 5) + (hh << 4)) ^ sw));
        ot[dt] = MFMA32(vf, pb[cc], ot[dt]);
      }
    }
    asm volatile("s_waitcnt vmcnt(0) lgkmcnt(0)" ::: "memory");
    __builtin_amdgcn_s_barrier();
  }
  const float linv = 1.f / lrun;
  const int b = bh / 12, h = bh - b * 12;
  u16* po = ao + ((size_t)(b*1024 + qrow)) * 768 + h*64;
#pragma unroll
  for (int dt = 0; dt < 2; ++dt) {
#pragma unroll
    for (int g = 0; g < 4; ++g) {
      ushort4 o4;
      o4.x = f2b(ot[dt][4*g + 0] * linv);
      o4.y = f2b(ot[dt][4*g + 1] * linv);
      o4.z = f2b(ot[dt][4*g + 2] * linv);
      o4.w = f2b(ot[dt][4*g + 3] * linv);
      *(ushort4*)(po + dt*32 + g*8 + hh*4) = o4;
    }
  }
}

// ---------------------------------------------------------------- proj GEMM
__global__ __launch_bounds__(256) void gemm_proj(
    const u16* __restrict__ ab, const u16* __restrict__ wb,
    const float* __restrict__ bias, float* __restrict__ out)
{
  __shared__ u16 lA[2][128*32];
  __shared__ u16 lB[2][128*32];
  const int tid = threadIdx.x;
  const int lane = tid & 63;
  const int wv = tid >> 6;
  const int wr = wv >> 1, wc = wv & 1;
  const int m0 = blockIdx.x << 7;
  const int o0 = blockIdx.y << 7;
  f32x4 acc[4][4] = {};
  const int srow = tid >> 2;
  const int sb   = (((tid & 3) ^ ((srow >> 1) & 3)) << 4);
  const char* gA0 = (const char*)(ab + (size_t)(m0 + srow)      * 768) + sb;
  const char* gA1 = (const char*)(ab + (size_t)(m0 + 64 + srow) * 768) + sb;
  const char* gB0 = (const char*)(wb + (size_t)(o0 + srow)      * 768) + sb;
  const char* gB1 = (const char*)(wb + (size_t)(o0 + 64 + srow) * 768) + sb;
  char* sA = (char*)lA + tid * 16;
  char* sB = (char*)lB + tid * 16;
  const int frow = lane & 15;
  const int fk   = (((lane >> 4) ^ ((frow >> 1) & 3)) << 4);

  QKV_STAGE(0, 0);
  asm volatile("s_waitcnt vmcnt(0) lgkmcnt(0)" ::: "memory");
  __builtin_amdgcn_s_barrier();
  for (int kt = 0; kt < 24; ++kt) {
    const int cur = kt & 1;
    if (kt < 23) QKV_STAGE(cur ^ 1, kt + 1);
    const char* bA = (const char*)lA + (cur << 13);
    const char* bB = (const char*)lB + (cur << 13);
    bf16x8 af[4], bfr[4];
#pragma unroll
    for (int m = 0; m < 4; ++m)
      af[m] = *(const bf16x8*)(bA + ((wr*64 + m*16 + frow) << 6) + fk);
#pragma unroll
    for (int n = 0; n < 4; ++n)
      bfr[n] = *(const bf16x8*)(bB + ((wc*64 + n*16 + frow) << 6) + fk);
#pragma unroll
    for (int m = 0; m < 4; ++m)
#pragma unroll
      for (int n = 0; n < 4; ++n)
        acc[m][n] = MFMA16(af[m], bfr[n], acc[m][n]);
    asm volatile("s_waitcnt vmcnt(0) lgkmcnt(0)" ::: "memory");
    __builtin_amdgcn_s_barrier();
  }
#pragma unroll
  for (int n = 0; n < 4; ++n) {
    const int go = o0 + wc*64 + n*16 + (lane & 15);
    const float bv = bias[go];
#pragma unroll
    for (int m = 0; m < 4; ++m) {
#pragma unroll
      for (int r = 0; r < 4; ++r) {
        const int gm = m0 + wr*64 + m*16 + ((lane >> 4) << 2) + r;
        out[(size_t)gm * 768 + go] = acc[m][n][r] + bv;
      }
    }
  }
}

// ---------------------------------------------------------------- launch
extern "C" void kernel_launch(void* const* d_in, const int* in_sizes, int n_in,
                              void* d_out, int out_size, void* d_ws, size_t ws_size,
                              hipStream_t stream)
{
  (void)in_sizes; (void)n_in; (void)out_size; (void)ws_size;
  const float* x  = (const float*)d_in[0];
  const float* wq = (const float*)d_in[1];
  const float* wp = (const float*)d_in[2];
  const float* bp = (const float*)d_in[3];
  float* out = (float*)d_out;
  char* ws = (char*)d_ws;
  u16* xb     = (u16*)(ws);              // 25,165,824  x bf16 [16384][768]
  u16* wqkvb  = (u16*)(ws + 25165824);   //  3,538,944  w_qkv bf16
  u16* wprojb = (u16*)(ws + 28704768);   //  1,179,648  w_proj bf16
  u16* qa     = (u16*)(ws + 29884416);   // 25,165,824  q  [192][1024][64] (pre-scaled)
  u16* ka     = (u16*)(ws + 55050240);   // 25,165,824  k  [192][1024][64]
  u16* vta    = (u16*)(ws + 80216064);   // 25,165,824  v^T[192][64][1024]
  u16* ao     = xb;                      // alias: xb dead after gemm_qkv

  cvt_bf16<<<2048, 256, 0, stream>>>((const float4*)x,  (ushort4*)xb,     3145728);
  cvt_bf16<<<1024, 256, 0, stream>>>((const float4*)wq, (ushort4*)wqkvb,   442368);
  cvt_bf16<<< 576, 256, 0, stream>>>((const float4*)wp, (ushort4*)wprojb,  147456);
  gemm_qkv<<<dim3(128, 18), 256, 0, stream>>>(xb, wqkvb, qa, ka, vta);
  attn_fwd<<<dim3(192, 4), 512, 0, stream>>>(qa, ka, vta, ao);
  gemm_proj<<<dim3(128, 6), 256, 0, stream>>>(ao, wprojb, bp, out);
}